// Round 7
// baseline (569.344 us; speedup 1.0000x reference)
//
#include <hip/hip_runtime.h>

typedef unsigned short u16;
typedef short s16x4 __attribute__((ext_vector_type(4)));
typedef short s16x8 __attribute__((ext_vector_type(8)));
typedef float f32x4 __attribute__((ext_vector_type(4)));

#define DEVFN __device__ __forceinline__

// problem constants
constexpr long AW_OFF  = 4194304;               // attn_output elems (2*2048*1024)
constexpr long PAT_OFF = AW_OFF + 134217728;    // + attn_weights elems (2*16*2048*2048)
constexpr float EXPSC  = 0.18033688011f;        // 0.125 * log2(e)

DEVFN u16 f2bf(float x) {
  unsigned u = __builtin_bit_cast(unsigned, x);
  unsigned r = (u + 0x7fffu + ((u >> 16) & 1u)) >> 16;   // RNE
  return (u16)r;
}

DEVFN void gld16(const u16* g, u16* l) {
  __builtin_amdgcn_global_load_lds(
      (const __attribute__((address_space(1))) unsigned int*)g,
      (__attribute__((address_space(3))) unsigned int*)l, 16, 0, 0);
}

// ---------------- fp32 -> bf16 elementwise, 3 tensors ----------------
__global__ __launch_bounds__(256) void k_cvt3(const float* __restrict__ a,
                                              const float* __restrict__ b,
                                              const float* __restrict__ c,
                                              u16* __restrict__ out, int n4) {
  int i = blockIdx.x * 256 + threadIdx.x;
  if (i >= n4) return;
  const float* in = (blockIdx.y == 0) ? a : (blockIdx.y == 1) ? b : c;
  float4 v = ((const float4*)in)[i];
  s16x4 o; o[0] = f2bf(v.x); o[1] = f2bf(v.y); o[2] = f2bf(v.z); o[3] = f2bf(v.w);
  ((s16x4*)(out + (long)blockIdx.y * 4194304))[i] = o;
}

// ---------------- pack 3 bias vectors contiguous ----------------
__global__ __launch_bounds__(256) void k_pack3(const float* __restrict__ a,
                                               const float* __restrict__ b,
                                               const float* __restrict__ c,
                                               float* __restrict__ out) {
  int i = blockIdx.x * 256 + threadIdx.x;   // grid 12 -> 3072
  const float* in = (i < 1024) ? a : (i < 2048) ? b : c;
  out[i] = in[i & 1023];
}

// ---------------- merged weight transposes: 7 slices of [1024,1024] ----------------
__global__ __launch_bounds__(256) void k_trW(const float* __restrict__ Wq,
                                             const float* __restrict__ Wk,
                                             const float* __restrict__ Wv,
                                             const float* __restrict__ Wo,
                                             const float* __restrict__ Wa,
                                             u16* __restrict__ Wqt,
                                             u16* __restrict__ Wot,
                                             u16* __restrict__ Wat) {
  __shared__ u16 tile[32][33];
  const int z = blockIdx.z;
  const float* in;
  u16* outp;
  if (z == 0)      { in = Wq; outp = Wqt; }
  else if (z == 1) { in = Wk; outp = Wqt + 1048576; }
  else if (z == 2) { in = Wv; outp = Wqt + 2097152; }
  else if (z == 3) { in = Wo; outp = Wot; }
  else             { in = Wa + (long)(z - 4) * 1048576; outp = Wat + (long)(z - 4) * 1048576; }
  int k0 = blockIdx.y * 32, n0 = blockIdx.x * 32;
  int tx = threadIdx.x & 31, ty = threadIdx.x >> 5;
#pragma unroll
  for (int i = 0; i < 4; ++i)
    tile[ty + i * 8][tx] = f2bf(in[(long)(k0 + ty + i * 8) * 1024 + (n0 + tx)]);
  __syncthreads();
#pragma unroll
  for (int i = 0; i < 4; ++i)
    outp[(long)(n0 + ty + i * 8) * 1024 + (k0 + tx)] = tile[tx][ty + i * 8];
}

// ---------------- tiled transpose: out[n][k] = bf16(in[k][n]) ----------------
template <bool IN_F32>
__global__ __launch_bounds__(256) void k_tr(const void* __restrict__ inv,
                                            u16* __restrict__ out,
                                            long ldin, long ldout,
                                            long inz1, long inz2, long outz, int zdiv) {
  __shared__ u16 tile[32][33];
  int z = blockIdx.z;
  long ioff = (long)(z / zdiv) * inz1 + (long)(z % zdiv) * inz2;
  int k0 = blockIdx.y * 32, n0 = blockIdx.x * 32;
  int tx = threadIdx.x, ty = threadIdx.y;
#pragma unroll
  for (int i = 0; i < 4; ++i) {
    long k = k0 + ty + i * 8, n = n0 + tx;
    u16 v;
    if constexpr (IN_F32) v = f2bf(((const float*)inv)[ioff + k * ldin + n]);
    else                  v = ((const u16*)inv)[ioff + k * ldin + n];
    tile[ty + i * 8][tx] = v;
  }
  __syncthreads();
  long ooff = (long)z * outz;
#pragma unroll
  for (int i = 0; i < 4; ++i) {
    long n = n0 + ty + i * 8, k = k0 + tx;
    out[ooff + n * ldout + k] = tile[tx][ty + i * 8];
  }
}

// ---------------- 128x128 NT GEMM core (shared by the GEMM kernels) ----------------
// Stages A[128][BKslice]/B into swizzled LDS and accumulates acc[4][4].
// T2 XOR swizzle: physical 16B unit p holds source unit p ^ (row&7).
#define GEMM_CORE(Ab, Bb, lda, ldb, K)                                              \
  f32x4 acc[4][4] = {};                                                             \
  for (int k0 = 0; k0 < (K); k0 += 64) {                                            \
    _Pragma("unroll")                                                               \
    for (int it = 0; it < 4; ++it) {                                                \
      const int u = it * 256 + tid;                                                 \
      const int r = u >> 3, p = u & 7;                                              \
      const int cg = (p ^ (r & 7)) * 8;                                             \
      gld16((Ab) + (long)(row0 + r) * (lda) + (k0 + cg), &At[r][p * 8]);            \
      gld16((Bb) + (long)(col0 + r) * (ldb) + (k0 + cg), &Bt[r][p * 8]);            \
    }                                                                               \
    __syncthreads();                                                                \
    _Pragma("unroll")                                                               \
    for (int kk = 0; kk < 2; ++kk) {                                                \
      s16x8 af[4], bf[4];                                                           \
      _Pragma("unroll")                                                             \
      for (int m = 0; m < 4; ++m)                                                   \
        af[m] = *(const s16x8*)&At[wm * 64 + m * 16 + lk][((kk * 4 + g) ^ (lk & 7)) * 8]; \
      _Pragma("unroll")                                                             \
      for (int n = 0; n < 4; ++n)                                                   \
        bf[n] = *(const s16x8*)&Bt[wn * 64 + n * 16 + lk][((kk * 4 + g) ^ (lk & 7)) * 8]; \
      _Pragma("unroll")                                                             \
      for (int m = 0; m < 4; ++m)                                                   \
        _Pragma("unroll")                                                           \
        for (int n = 0; n < 4; ++n)                                                 \
          acc[m][n] = __builtin_amdgcn_mfma_f32_16x16x32_bf16(af[m], bf[n], acc[m][n], 0, 0, 0); \
    }                                                                               \
    __syncthreads();                                                                \
  }

// ---------------- generic batched NT GEMM (outproj) ----------------
template <typename OutT>
__global__ __launch_bounds__(256) void k_gemm_nt(
    const u16* __restrict__ Ap, const u16* __restrict__ Bp, OutT* __restrict__ Cp,
    const float* __restrict__ bias, float alpha, int K,
    long lda, long ldb, long ldc,
    long saz1, long saz2, long sbz1, long sbz2, long scz1, long scz2,
    long sbias, int zdiv) {
  __shared__ __align__(16) u16 At[128][64];
  __shared__ __align__(16) u16 Bt[128][64];
  const int tid = threadIdx.x, lane = tid & 63, wid = tid >> 6;
  const int wm = wid >> 1, wn = wid & 1;

  const int gx = gridDim.x, gy = gridDim.y;
  int id = (blockIdx.z * gy + blockIdx.y) * gx + blockIdx.x;
  const int nb = gx * gy * (int)gridDim.z;
  if ((nb & 7) == 0) id = (id & 7) * (nb >> 3) + (id >> 3);
  const int bxi = id % gx, byi = (id / gx) % gy, bzi = id / (gx * gy);

  const int z = bzi, z1 = z / zdiv, z2 = z % zdiv;
  const u16* Ab = Ap + (long)z1 * saz1 + (long)z2 * saz2;
  const u16* Bb = Bp + (long)z1 * sbz1 + (long)z2 * sbz2;
  OutT* C = Cp + (long)z1 * scz1 + (long)z2 * scz2;
  const float* bv = bias ? bias + (long)z2 * sbias : nullptr;
  const int row0 = byi * 128, col0 = bxi * 128;
  const int lk = lane & 15, g = lane >> 4;

  GEMM_CORE(Ab, Bb, lda, ldb, K)

#pragma unroll
  for (int m = 0; m < 4; ++m) {
    const int grow = row0 + wm * 64 + m * 16 + g * 4;
#pragma unroll
    for (int r = 0; r < 4; ++r) {
#pragma unroll
      for (int n = 0; n < 4; ++n) {
        const int gcol = col0 + wn * 64 + n * 16 + lk;
        float v = alpha * acc[m][n][r] + (bv ? bv[gcol] : 0.0f);
        if constexpr (sizeof(OutT) == 2) C[(long)(grow + r) * ldc + gcol] = f2bf(v);
        else                             C[(long)(grow + r) * ldc + gcol] = v;
      }
    }
  }
}

// ---------------- 9-way merged projection GEMM: proj q/k/v + aspect q/k ----------------
// z 0..2: qp/kp/vp = qb[z] @ Wqt[z] + pbias[z];  z 3..8: qa slice = qb[q|k] @ Wat[a] + ba[a]
__global__ __launch_bounds__(256) void k_proj9(
    const u16* __restrict__ qb, const u16* __restrict__ Wqt, const u16* __restrict__ Wat,
    u16* __restrict__ qp, u16* __restrict__ qa,
    const float* __restrict__ pbias, const float* __restrict__ ba) {
  __shared__ __align__(16) u16 At[128][64];
  __shared__ __align__(16) u16 Bt[128][64];
  const int tid = threadIdx.x, lane = tid & 63, wid = tid >> 6;
  const int wm = wid >> 1, wn = wid & 1;

  const int gx = gridDim.x, gy = gridDim.y;
  int id = (blockIdx.z * gy + blockIdx.y) * gx + blockIdx.x;
  const int nb = gx * gy * (int)gridDim.z;
  id = (id & 7) * (nb >> 3) + (id >> 3);
  const int bxi = id % gx, byi = (id / gx) % gy, z = id / (gx * gy);

  const u16 *Ab, *Bb;
  u16* C;
  const float* bv;
  if (z < 3) {
    Ab = qb + (long)z * 4194304; Bb = Wqt + (long)z * 1048576;
    C = qp + (long)z * 4194304;  bv = pbias + (long)z * 1024;
  } else {
    const int z1 = (z - 3) / 3, z2 = (z - 3) % 3;
    Ab = qb + (long)z1 * 4194304; Bb = Wat + (long)z2 * 1048576;
    C = qa + (long)z1 * 12582912 + (long)z2 * 4194304; bv = ba + (long)z2 * 1024;
  }
  const int row0 = byi * 128, col0 = bxi * 128;
  const int lk = lane & 15, g = lane >> 4;

  GEMM_CORE(Ab, Bb, 1024, 1024, 1024)

#pragma unroll
  for (int m = 0; m < 4; ++m) {
    const int grow = row0 + wm * 64 + m * 16 + g * 4;
#pragma unroll
    for (int r = 0; r < 4; ++r) {
#pragma unroll
      for (int n = 0; n < 4; ++n) {
        const int gcol = col0 + wn * 64 + n * 16 + lk;
        C[(long)(grow + r) * 1024 + gcol] = f2bf(acc[m][n][r] + bv[gcol]);
      }
    }
  }
}

// ---------------- mixed launch: attn-weights writer (HBM-bound) + pattern logits ----
// 9728 blocks: per XCD chunk of 1216, interleave 16 writer : 3 pattern blocks so
// every CU co-hosts both kinds -> MFMA (patterns) overlaps HBM writes (weights).
__global__ __launch_bounds__(256) void k_mix(
    const u16* __restrict__ qp, const u16* __restrict__ kp,
    const u16* __restrict__ qa, const u16* __restrict__ ka,
    float* __restrict__ aw, float* __restrict__ pat,
    const float* __restrict__ rinv) {
  __shared__ __align__(16) u16 At[128][64];
  __shared__ __align__(16) u16 Bt[128][64];
  const int tid = threadIdx.x, lane = tid & 63, wid = tid >> 6;
  const int wm = wid >> 1, wn = wid & 1;
  const int lk = lane & 15, g = lane >> 4;

  const int id = blockIdx.x;
  const int cx = id & 7, pos = id >> 3;          // XCD chunk, position in chunk (1216)
  const int grp = pos / 19, r19 = pos % 19;      // 19 = 16 writer + 3 pattern
  const bool isw = (r19 < 16);
  int z, by, bx, K;
  const u16 *Ab, *Bb;
  float* C;
  if (isw) {
    const int w = cx * 1024 + grp * 16 + r19;    // [0,8192)
    z = w >> 8; const int t = w & 255; by = t >> 4; bx = t & 15;
    Ab = qp + (long)(z >> 4) * 2097152 + (long)(z & 15) * 64;
    Bb = kp + (long)(z >> 4) * 2097152 + (long)(z & 15) * 64;
    C  = aw + (long)z * 4194304;
    K = 64;
  } else {
    const int p = cx * 192 + grp * 3 + (r19 - 16);  // [0,1536)
    z = p >> 8; const int t = p & 255; by = t >> 4; bx = t & 15;
    Ab = qa + (long)z * 2097152;
    Bb = ka + (long)z * 2097152;
    C  = pat + (long)z * 4194304;
    K = 1024;
  }
  const int row0 = by * 128, col0 = bx * 128;

  GEMM_CORE(Ab, Bb, 1024, 1024, K)

  const float* rz = rinv + (long)z * 2048;
#pragma unroll
  for (int m = 0; m < 4; ++m) {
    const int grow = row0 + wm * 64 + m * 16 + g * 4;
#pragma unroll
    for (int r = 0; r < 4; ++r) {
      const float iv = isw ? rz[grow + r] : 0.0f;
#pragma unroll
      for (int n = 0; n < 4; ++n) {
        const int gcol = col0 + wn * 64 + n * 16 + lk;
        float v;
        if (isw) v = exp2f(acc[m][n][r] * EXPSC) * iv;
        else     v = 0.125f * acc[m][n][r];
        C[(long)(grow + r) * 2048 + gcol] = v;
      }
    }
  }
}

// ---------------- flash attention: ctx[b,s,h*64+d], rinv[bh,q] = 1/sum(exp) ----------------
__global__ __launch_bounds__(256) void k_flash(
    const u16* __restrict__ qp, const u16* __restrict__ kp, const u16* __restrict__ vt,
    u16* __restrict__ ctx, float* __restrict__ rinv) {
  __shared__ __align__(16) char lds[49152];
  u16* Qt = (u16*)lds;            // [128][64]
  u16* Kt = (u16*)(lds + 16384);  // [128][64]
  u16* Vl = (u16*)(lds + 32768);  // [64][128]
  const int tid = threadIdx.x, lane = tid & 63, wid = tid >> 6;
  const int wk = wid >> 1, wq = wid & 1;

  const int gx = gridDim.x;
  int id = blockIdx.y * gx + blockIdx.x;
  const int nb = gx * (int)gridDim.y;
  if ((nb & 7) == 0) id = (id & 7) * (nb >> 3) + (id >> 3);
  const int bh = id / gx, q0 = (id % gx) * 128;

  const long qkbase = (long)(bh >> 4) * 2097152 + (long)(bh & 15) * 64;
  const long vbase = (long)bh * 131072;
  const int lk = lane & 15, g = lane >> 4;
  const int sp = lane & 7;
  const int sr = lane >> 3;

#pragma unroll
  for (int i = 0; i < 4; ++i) {
    const int rr = (wid * 4 + i) * 8 + sr;
    gld16(qp + qkbase + (long)(q0 + rr) * 1024 + ((sp ^ (rr & 7)) * 8), Qt + rr * 64 + sp * 8);
  }
  __syncthreads();

  s16x8 qf[2][4];
#pragma unroll
  for (int kk = 0; kk < 2; ++kk) {
#pragma unroll
    for (int nq = 0; nq < 4; ++nq)
      qf[kk][nq] = *(const s16x8*)(Qt + (wq * 64 + nq * 16 + lk) * 64 + ((kk * 4 + g) ^ (lk & 7)) * 8);
  }

  f32x4 cacc[4][4] = {};
  float rs[4] = {0.f, 0.f, 0.f, 0.f};

  for (int t = 0; t < 16; ++t) {
    const int kb = t * 128;
#pragma unroll
    for (int i = 0; i < 4; ++i) {
      const int rr = (wid * 4 + i) * 8 + sr;
      gld16(kp + qkbase + (long)(kb + rr) * 1024 + ((sp ^ (rr & 7)) * 8), Kt + rr * 64 + sp * 8);
      const int dd = (wid * 4 + i) * 4 + g;
      const int pv = lane & 15;
      const int cv = (pv & 8) | ((pv ^ dd) & 7);
      gld16(vt + vbase + (long)dd * 2048 + (kb + cv * 8), Vl + dd * 128 + pv * 8);
    }
    __syncthreads();

    f32x4 st[4][4] = {};
#pragma unroll
    for (int kk = 0; kk < 2; ++kk) {
      s16x8 af[4];
#pragma unroll
      for (int mk = 0; mk < 4; ++mk)
        af[mk] = *(const s16x8*)(Kt + (wk * 64 + mk * 16 + lk) * 64 + ((kk * 4 + g) ^ (lk & 7)) * 8);
#pragma unroll
      for (int mk = 0; mk < 4; ++mk)
#pragma unroll
        for (int nq = 0; nq < 4; ++nq)
          st[mk][nq] = __builtin_amdgcn_mfma_f32_16x16x32_bf16(af[mk], qf[kk][nq], st[mk][nq], 0, 0, 0);
    }
#pragma unroll
    for (int mk = 0; mk < 4; ++mk)
#pragma unroll
      for (int nq = 0; nq < 4; ++nq)
#pragma unroll
        for (int j = 0; j < 4; ++j) {
          const float p = exp2f(st[mk][nq][j] * EXPSC);
          st[mk][nq][j] = p;
          rs[nq] += p;
        }
#pragma unroll
    for (int ks = 0; ks < 2; ++ks) {
      s16x8 pb[4];
#pragma unroll
      for (int nq = 0; nq < 4; ++nq) {
        s16x8 b;
#pragma unroll
        for (int j = 0; j < 4; ++j) {
          b[j]     = (short)f2bf(st[2 * ks][nq][j]);
          b[4 + j] = (short)f2bf(st[2 * ks + 1][nq][j]);
        }
        pb[nq] = b;
      }
#pragma unroll
      for (int md = 0; md < 4; ++md) {
        const int rowv = md * 16 + lk;
        const int u0 = ks * 4 + (g >> 1);
        const int p0 = wk * 8 + ((u0 ^ (rowv & 7)) & 7);
        const int p2 = wk * 8 + (((u0 + 2) ^ (rowv & 7)) & 7);
        const u16* vb0 = Vl + rowv * 128 + p0 * 8 + (g & 1) * 4;
        const u16* vb2 = Vl + rowv * 128 + p2 * 8 + (g & 1) * 4;
        s16x4 lo = *(const s16x4*)vb0;
        s16x4 hi = *(const s16x4*)vb2;
        s16x8 vf;
        vf[0] = lo[0]; vf[1] = lo[1]; vf[2] = lo[2]; vf[3] = lo[3];
        vf[4] = hi[0]; vf[5] = hi[1]; vf[6] = hi[2]; vf[7] = hi[3];
#pragma unroll
        for (int nq = 0; nq < 4; ++nq)
          cacc[md][nq] = __builtin_amdgcn_mfma_f32_16x16x32_bf16(vf, pb[nq], cacc[md][nq], 0, 0, 0);
      }
    }
    __syncthreads();
  }

#pragma unroll
  for (int nq = 0; nq < 4; ++nq) {
    rs[nq] += __shfl_xor(rs[nq], 16, 64);
    rs[nq] += __shfl_xor(rs[nq], 32, 64);
  }
  float* ctxl = (float*)lds;            // [64][129]
  float* rsl  = (float*)(lds + 33024);  // [128]
  if (wk == 1) {
#pragma unroll
    for (int md = 0; md < 4; ++md)
#pragma unroll
      for (int nq = 0; nq < 4; ++nq)
#pragma unroll
        for (int r = 0; r < 4; ++r)
          ctxl[(md * 16 + g * 4 + r) * 129 + wq * 64 + nq * 16 + lk] = cacc[md][nq][r];
    if (lane < 16)
#pragma unroll
      for (int nq = 0; nq < 4; ++nq) rsl[wq * 64 + nq * 16 + lane] = rs[nq];
  }
  __syncthreads();
  if (wk == 0) {
#pragma unroll
    for (int md = 0; md < 4; ++md)
#pragma unroll
      for (int nq = 0; nq < 4; ++nq)
#pragma unroll
        for (int r = 0; r < 4; ++r) {
          const int idx = (md * 16 + g * 4 + r) * 129 + wq * 64 + nq * 16 + lk;
          ctxl[idx] += cacc[md][nq][r];
        }
    if (lane < 16)
#pragma unroll
      for (int nq = 0; nq < 4; ++nq) {
        const int qi = wq * 64 + nq * 16 + lane;
        const float inv = 1.0f / (rsl[qi] + rs[nq]);
        rsl[qi] = inv;
        rinv[(long)bh * 2048 + q0 + qi] = inv;
      }
  }
  __syncthreads();
  const int qr = tid >> 1, half = tid & 1;
  const float inv = rsl[qr];
  u16* dst = ctx + (long)(bh >> 4) * 2097152 + (long)(q0 + qr) * 1024 + (long)(bh & 15) * 64 + half * 32;
#pragma unroll
  for (int c = 0; c < 4; ++c) {
    s16x8 o;
#pragma unroll
    for (int j = 0; j < 8; ++j) {
      const int d = half * 32 + c * 8 + j;
      o[j] = (short)f2bf(ctxl[d * 129 + qr] * inv);
    }
    ((s16x8*)dst)[c] = o;
  }
}

// ---------------- in-place row softmax, rows of 2048 fp32 ----------------
__global__ __launch_bounds__(256) void k_softmax(float* __restrict__ base) {
  float* p = base + (long)blockIdx.x * 2048;
  const int t = threadIdx.x;
  float4 v0 = ((const float4*)p)[t];
  float4 v1 = ((const float4*)p)[t + 256];
  float m = fmaxf(fmaxf(fmaxf(v0.x, v0.y), fmaxf(v0.z, v0.w)),
                  fmaxf(fmaxf(v1.x, v1.y), fmaxf(v1.z, v1.w)));
#pragma unroll
  for (int i = 32; i >= 1; i >>= 1) m = fmaxf(m, __shfl_xor(m, i, 64));
  __shared__ float sm[4], ss[4];
  if ((t & 63) == 0) sm[t >> 6] = m;
  __syncthreads();
  m = fmaxf(fmaxf(sm[0], sm[1]), fmaxf(sm[2], sm[3]));
  float4 e0, e1;
  e0.x = __expf(v0.x - m); e0.y = __expf(v0.y - m); e0.z = __expf(v0.z - m); e0.w = __expf(v0.w - m);
  e1.x = __expf(v1.x - m); e1.y = __expf(v1.y - m); e1.z = __expf(v1.z - m); e1.w = __expf(v1.w - m);
  float s = (e0.x + e0.y + e0.z + e0.w) + (e1.x + e1.y + e1.z + e1.w);
#pragma unroll
  for (int i = 32; i >= 1; i >>= 1) s += __shfl_xor(s, i, 64);
  if ((t & 63) == 0) ss[t >> 6] = s;
  __syncthreads();
  s = ss[0] + ss[1] + ss[2] + ss[3];
  float inv = 1.0f / s;
  e0.x *= inv; e0.y *= inv; e0.z *= inv; e0.w *= inv;
  e1.x *= inv; e1.y *= inv; e1.z *= inv; e1.w *= inv;
  ((float4*)p)[t] = e0;
  ((float4*)p)[t + 256] = e1;
}

// ---------------- launch ----------------
extern "C" void kernel_launch(void* const* d_in, const int* in_sizes, int n_in,
                              void* d_out, int out_size, void* d_ws, size_t ws_size,
                              hipStream_t stream) {
  const float* query = (const float*)d_in[0];
  const float* key   = (const float*)d_in[1];
  const float* value = (const float*)d_in[2];
  const float* Wq = (const float*)d_in[3];
  const float* bq = (const float*)d_in[4];
  const float* Wk = (const float*)d_in[5];
  const float* bk = (const float*)d_in[6];
  const float* Wv = (const float*)d_in[7];
  const float* bv = (const float*)d_in[8];
  const float* Wo = (const float*)d_in[9];
  const float* bo = (const float*)d_in[10];
  const float* Wa = (const float*)d_in[11];
  const float* ba = (const float*)d_in[12];
  float* out = (float*)d_out;
  char* ws = (char*)d_ws;

  // workspace layout (bytes)
  u16* qb  = (u16*)(ws + 0);           // [3][4096,1024] bf16 q,k,v (contiguous)
  u16* Wqt = (u16*)(ws + 25165824);    // [3][1024,1024] Wq^T,Wk^T,Wv^T bf16 (contig; reused as rinv)
  u16* Wot = (u16*)(ws + 31457280);
  u16* Wat = (u16*)(ws + 33554432);    // [3,1024,1024]
  u16* qp  = (u16*)(ws + 39845888);    // [3][4096,1024] projected q,k,v (contiguous)
  u16* kp  = (u16*)(ws + 48234496);
  u16* vp  = (u16*)(ws + 56623104);
  u16* vt  = (u16*)(ws + 65011712);    // [B,H,64,2048] V^T per head
  u16* ctx = (u16*)(ws + 73400320);    // [4096,1024]
  u16* qa  = (u16*)(ws + 81788928);    // [2][3][4096,1024] aspect q then aspect k (contiguous)
  float* rinv  = (float*)(ws + 25165824);   // [32,2048] (overwrites Wqt after proj)
  float* pbias = (float*)(ws + 132120576);  // [3,1024] packed bq,bk,bv

  dim3 b256(256);
  dim3 trb(32, 8);

  // bf16 conversions of q,k,v activations (one launch) + bias pack
  k_cvt3<<<dim3(4096, 3), b256, 0, stream>>>(query, key, value, qb, 1048576);
  k_pack3<<<12, b256, 0, stream>>>(bq, bk, bv, pbias);

  // all weight transposes in ONE launch (z = 0..6)
  k_trW<<<dim3(32, 32, 7), b256, 0, stream>>>(Wq, Wk, Wv, Wo, Wa, Wqt, Wot, Wat);

  // proj q/k/v + aspect q/k in ONE launch (9 z-slices, 2304 blocks)
  k_proj9<<<dim3(8, 32, 9), b256, 0, stream>>>(qb, Wqt, Wat, qp, qa, pbias, ba);

  // per-head V^T: vt[b,h][d][s]  (z = b*16+h)
  k_tr<false><<<dim3(2, 64, 32), trb, 0, stream>>>(
      vp, vt, 1024, 2048, 2097152, 64, 131072, 16);

  // flash attention: ctx (bf16) + rinv
  k_flash<<<dim3(16, 32), b256, 0, stream>>>(qp, kp, vt, ctx, rinv);

  // mixed launch: attn_weights single-pass writer + pattern logits (overlapped)
  k_mix<<<9728, b256, 0, stream>>>(qp, kp, qa, qa + 12582912,
                                   out + AW_OFF, out + PAT_OFF, rinv);

  // softmax over patterns only (3*B*S = 12288 rows of 2048)
  k_softmax<<<12288, b256, 0, stream>>>(out + PAT_OFF);

  // output projection -> d_out attn_output
  k_gemm_nt<float><<<dim3(8, 32, 1), b256, 0, stream>>>(
      ctx, Wot, out, bo, 1.0f, 1024, 1024, 1024, 1024, 0, 0, 0, 0, 0, 0, 0, 1);
}

// Round 8
// 532.747 us; speedup vs baseline: 1.0687x; 1.0687x over previous
//
#include <hip/hip_runtime.h>

typedef unsigned short u16;
typedef short s16x4 __attribute__((ext_vector_type(4)));
typedef short s16x8 __attribute__((ext_vector_type(8)));
typedef float f32x4 __attribute__((ext_vector_type(4)));

#define DEVFN __device__ __forceinline__

// problem constants
constexpr long AW_OFF  = 4194304;               // attn_output elems (2*2048*1024)
constexpr long PAT_OFF = AW_OFF + 134217728;    // + attn_weights elems (2*16*2048*2048)
constexpr float EXPSC  = 0.18033688011f;        // 0.125 * log2(e)

DEVFN u16 f2bf(float x) {
  unsigned u = __builtin_bit_cast(unsigned, x);
  unsigned r = (u + 0x7fffu + ((u >> 16) & 1u)) >> 16;   // RNE
  return (u16)r;
}

DEVFN void gld16(const u16* g, u16* l) {
  __builtin_amdgcn_global_load_lds(
      (const __attribute__((address_space(1))) unsigned int*)g,
      (__attribute__((address_space(3))) unsigned int*)l, 16, 0, 0);
}

// ---------------- fp32 -> bf16 elementwise, 3 tensors ----------------
__global__ __launch_bounds__(256) void k_cvt3(const float* __restrict__ a,
                                              const float* __restrict__ b,
                                              const float* __restrict__ c,
                                              u16* __restrict__ out, int n4) {
  int i = blockIdx.x * 256 + threadIdx.x;
  if (i >= n4) return;
  const float* in = (blockIdx.y == 0) ? a : (blockIdx.y == 1) ? b : c;
  float4 v = ((const float4*)in)[i];
  s16x4 o; o[0] = f2bf(v.x); o[1] = f2bf(v.y); o[2] = f2bf(v.z); o[3] = f2bf(v.w);
  ((s16x4*)(out + (long)blockIdx.y * 4194304))[i] = o;
}

// ---------------- pack 3 bias vectors contiguous ----------------
__global__ __launch_bounds__(256) void k_pack3(const float* __restrict__ a,
                                               const float* __restrict__ b,
                                               const float* __restrict__ c,
                                               float* __restrict__ out) {
  int i = blockIdx.x * 256 + threadIdx.x;   // grid 12 -> 3072
  const float* in = (i < 1024) ? a : (i < 2048) ? b : c;
  out[i] = in[i & 1023];
}

// ---------------- merged weight transposes: 7 slices of [1024,1024] ----------------
__global__ __launch_bounds__(256) void k_trW(const float* __restrict__ Wq,
                                             const float* __restrict__ Wk,
                                             const float* __restrict__ Wv,
                                             const float* __restrict__ Wo,
                                             const float* __restrict__ Wa,
                                             u16* __restrict__ Wqt,
                                             u16* __restrict__ Wot,
                                             u16* __restrict__ Wat) {
  __shared__ u16 tile[32][33];
  const int z = blockIdx.z;
  const float* in;
  u16* outp;
  if (z == 0)      { in = Wq; outp = Wqt; }
  else if (z == 1) { in = Wk; outp = Wqt + 1048576; }
  else if (z == 2) { in = Wv; outp = Wqt + 2097152; }
  else if (z == 3) { in = Wo; outp = Wot; }
  else             { in = Wa + (long)(z - 4) * 1048576; outp = Wat + (long)(z - 4) * 1048576; }
  int k0 = blockIdx.y * 32, n0 = blockIdx.x * 32;
  int tx = threadIdx.x & 31, ty = threadIdx.x >> 5;
#pragma unroll
  for (int i = 0; i < 4; ++i)
    tile[ty + i * 8][tx] = f2bf(in[(long)(k0 + ty + i * 8) * 1024 + (n0 + tx)]);
  __syncthreads();
#pragma unroll
  for (int i = 0; i < 4; ++i)
    outp[(long)(n0 + ty + i * 8) * 1024 + (k0 + tx)] = tile[tx][ty + i * 8];
}

// ---------------- tiled transpose: out[n][k] = bf16(in[k][n]) ----------------
template <bool IN_F32>
__global__ __launch_bounds__(256) void k_tr(const void* __restrict__ inv,
                                            u16* __restrict__ out,
                                            long ldin, long ldout,
                                            long inz1, long inz2, long outz, int zdiv) {
  __shared__ u16 tile[32][33];
  int z = blockIdx.z;
  long ioff = (long)(z / zdiv) * inz1 + (long)(z % zdiv) * inz2;
  int k0 = blockIdx.y * 32, n0 = blockIdx.x * 32;
  int tx = threadIdx.x, ty = threadIdx.y;
#pragma unroll
  for (int i = 0; i < 4; ++i) {
    long k = k0 + ty + i * 8, n = n0 + tx;
    u16 v;
    if constexpr (IN_F32) v = f2bf(((const float*)inv)[ioff + k * ldin + n]);
    else                  v = ((const u16*)inv)[ioff + k * ldin + n];
    tile[ty + i * 8][tx] = v;
  }
  __syncthreads();
  long ooff = (long)z * outz;
#pragma unroll
  for (int i = 0; i < 4; ++i) {
    long n = n0 + ty + i * 8, k = k0 + tx;
    out[ooff + n * ldout + k] = tile[tx][ty + i * 8];
  }
}

// ---------------- batched NT GEMM: C = f(alpha * A[M,K] @ B[N,K]^T) ----------------
// EPI 0: v = alpha*acc + bias[z2][col];  EPI 1: v = exp2(acc*EXPSC) * rinv[z][row]
// global_load_lds staging, LINEAR LDS dest + XOR-swizzled (p = c ^ (row&7), 16B units)
// global source and fragment reads -> conflict-free ds_read_b128 fragments.
// XCD-chunked bijective block swizzle (nb%8==0) for per-XCD L2 locality.
template <typename OutT, int EPI>
__global__ __launch_bounds__(256) void k_gemm_nt(
    const u16* __restrict__ Ap, const u16* __restrict__ Bp, OutT* __restrict__ Cp,
    const float* __restrict__ bias, const float* __restrict__ rinv, float alpha, int K,
    long lda, long ldb, long ldc,
    long saz1, long saz2, long sbz1, long sbz2, long scz1, long scz2,
    long sbias, int zdiv) {
  __shared__ __align__(16) u16 At[128][64];
  __shared__ __align__(16) u16 Bt[128][64];
  const int tid = threadIdx.x, lane = tid & 63, wid = tid >> 6;
  const int wm = wid >> 1, wn = wid & 1;

  const int gx = gridDim.x, gy = gridDim.y;
  int id = (blockIdx.z * gy + blockIdx.y) * gx + blockIdx.x;
  const int nb = gx * gy * (int)gridDim.z;
  if ((nb & 7) == 0) id = (id & 7) * (nb >> 3) + (id >> 3);
  const int bxi = id % gx, byi = (id / gx) % gy, bzi = id / (gx * gy);

  const int z = bzi, z1 = z / zdiv, z2 = z % zdiv;
  const u16* Ab = Ap + (long)z1 * saz1 + (long)z2 * saz2;
  const u16* Bb = Bp + (long)z1 * sbz1 + (long)z2 * sbz2;
  OutT* C = Cp + (long)z1 * scz1 + (long)z2 * scz2;
  const float* bv = bias ? bias + (long)z2 * sbias : nullptr;
  const int row0 = byi * 128, col0 = bxi * 128;
  const int lk = lane & 15, g = lane >> 4;

  f32x4 acc[4][4] = {};

  for (int k0 = 0; k0 < K; k0 += 64) {
#pragma unroll
    for (int it = 0; it < 4; ++it) {
      const int u = it * 256 + tid;          // 16B-unit index over the tile
      const int r = u >> 3, p = u & 7;       // row, physical unit in row
      const int cg = (p ^ (r & 7)) * 8;      // pre-swizzled source column (elems)
      gld16(Ab + (long)(row0 + r) * lda + (k0 + cg), &At[r][p * 8]);
      gld16(Bb + (long)(col0 + r) * ldb + (k0 + cg), &Bt[r][p * 8]);
    }
    __syncthreads();
#pragma unroll
    for (int kk = 0; kk < 2; ++kk) {
      s16x8 af[4], bf[4];
#pragma unroll
      for (int m = 0; m < 4; ++m)
        af[m] = *(const s16x8*)&At[wm * 64 + m * 16 + lk][((kk * 4 + g) ^ (lk & 7)) * 8];
#pragma unroll
      for (int n = 0; n < 4; ++n)
        bf[n] = *(const s16x8*)&Bt[wn * 64 + n * 16 + lk][((kk * 4 + g) ^ (lk & 7)) * 8];
#pragma unroll
      for (int m = 0; m < 4; ++m)
#pragma unroll
        for (int n = 0; n < 4; ++n)
          acc[m][n] = __builtin_amdgcn_mfma_f32_16x16x32_bf16(af[m], bf[n], acc[m][n], 0, 0, 0);
    }
    __syncthreads();
  }

  const float* rz = (EPI == 1) ? rinv + (long)z * 2048 : nullptr;
#pragma unroll
  for (int m = 0; m < 4; ++m) {
    const int grow = row0 + wm * 64 + m * 16 + g * 4;
#pragma unroll
    for (int r = 0; r < 4; ++r) {
      float iv = 0.0f;
      if constexpr (EPI == 1) iv = rz[grow + r];
#pragma unroll
      for (int n = 0; n < 4; ++n) {
        const int gcol = col0 + wn * 64 + n * 16 + lk;
        float v;
        if constexpr (EPI == 1) v = exp2f(acc[m][n][r] * EXPSC) * iv;
        else                    v = alpha * acc[m][n][r] + (bv ? bv[gcol] : 0.0f);
        if constexpr (sizeof(OutT) == 2) C[(long)(grow + r) * ldc + gcol] = f2bf(v);
        else                             C[(long)(grow + r) * ldc + gcol] = v;
      }
    }
  }
}

// ---------------- flash attention: ctx[b,s,h*64+d], rinv[bh,q] = 1/sum(exp) ----------------
// grid (S/128, B*H); 4 waves: wk = wid>>1 (k-half), wq = wid&1 (q-half).
// St[k][q] via mfma(K,Q) so P rows feed PV's B operand directly from registers.
__global__ __launch_bounds__(256) void k_flash(
    const u16* __restrict__ qp, const u16* __restrict__ kp, const u16* __restrict__ vt,
    u16* __restrict__ ctx, float* __restrict__ rinv) {
  __shared__ __align__(16) char lds[49152];
  u16* Qt = (u16*)lds;            // [128][64]
  u16* Kt = (u16*)(lds + 16384);  // [128][64]
  u16* Vl = (u16*)(lds + 32768);  // [64][128]
  const int tid = threadIdx.x, lane = tid & 63, wid = tid >> 6;
  const int wk = wid >> 1, wq = wid & 1;

  const int gx = gridDim.x;
  int id = blockIdx.y * gx + blockIdx.x;
  const int nb = gx * (int)gridDim.y;
  if ((nb & 7) == 0) id = (id & 7) * (nb >> 3) + (id >> 3);
  const int bh = id / gx, q0 = (id % gx) * 128;

  const long qkbase = (long)(bh >> 4) * 2097152 + (long)(bh & 15) * 64;
  const long vbase = (long)bh * 131072;
  const int lk = lane & 15, g = lane >> 4;
  const int sp = lane & 7;
  const int sr = lane >> 3;

#pragma unroll
  for (int i = 0; i < 4; ++i) {
    const int rr = (wid * 4 + i) * 8 + sr;
    gld16(qp + qkbase + (long)(q0 + rr) * 1024 + ((sp ^ (rr & 7)) * 8), Qt + rr * 64 + sp * 8);
  }
  __syncthreads();

  s16x8 qf[2][4];
#pragma unroll
  for (int kk = 0; kk < 2; ++kk) {
#pragma unroll
    for (int nq = 0; nq < 4; ++nq)
      qf[kk][nq] = *(const s16x8*)(Qt + (wq * 64 + nq * 16 + lk) * 64 + ((kk * 4 + g) ^ (lk & 7)) * 8);
  }

  f32x4 cacc[4][4] = {};
  float rs[4] = {0.f, 0.f, 0.f, 0.f};

  for (int t = 0; t < 16; ++t) {
    const int kb = t * 128;
#pragma unroll
    for (int i = 0; i < 4; ++i) {
      const int rr = (wid * 4 + i) * 8 + sr;
      gld16(kp + qkbase + (long)(kb + rr) * 1024 + ((sp ^ (rr & 7)) * 8), Kt + rr * 64 + sp * 8);
      const int dd = (wid * 4 + i) * 4 + g;
      const int pv = lane & 15;
      const int cv = (pv & 8) | ((pv ^ dd) & 7);
      gld16(vt + vbase + (long)dd * 2048 + (kb + cv * 8), Vl + dd * 128 + pv * 8);
    }
    __syncthreads();

    f32x4 st[4][4] = {};
#pragma unroll
    for (int kk = 0; kk < 2; ++kk) {
      s16x8 af[4];
#pragma unroll
      for (int mk = 0; mk < 4; ++mk)
        af[mk] = *(const s16x8*)(Kt + (wk * 64 + mk * 16 + lk) * 64 + ((kk * 4 + g) ^ (lk & 7)) * 8);
#pragma unroll
      for (int mk = 0; mk < 4; ++mk)
#pragma unroll
        for (int nq = 0; nq < 4; ++nq)
          st[mk][nq] = __builtin_amdgcn_mfma_f32_16x16x32_bf16(af[mk], qf[kk][nq], st[mk][nq], 0, 0, 0);
    }
#pragma unroll
    for (int mk = 0; mk < 4; ++mk)
#pragma unroll
      for (int nq = 0; nq < 4; ++nq)
#pragma unroll
        for (int j = 0; j < 4; ++j) {
          const float p = exp2f(st[mk][nq][j] * EXPSC);
          st[mk][nq][j] = p;
          rs[nq] += p;
        }
#pragma unroll
    for (int ks = 0; ks < 2; ++ks) {
      s16x8 pb[4];
#pragma unroll
      for (int nq = 0; nq < 4; ++nq) {
        s16x8 b;
#pragma unroll
        for (int j = 0; j < 4; ++j) {
          b[j]     = (short)f2bf(st[2 * ks][nq][j]);
          b[4 + j] = (short)f2bf(st[2 * ks + 1][nq][j]);
        }
        pb[nq] = b;
      }
#pragma unroll
      for (int md = 0; md < 4; ++md) {
        const int rowv = md * 16 + lk;
        const int u0 = ks * 4 + (g >> 1);
        const int p0 = wk * 8 + ((u0 ^ (rowv & 7)) & 7);
        const int p2 = wk * 8 + (((u0 + 2) ^ (rowv & 7)) & 7);
        const u16* vb0 = Vl + rowv * 128 + p0 * 8 + (g & 1) * 4;
        const u16* vb2 = Vl + rowv * 128 + p2 * 8 + (g & 1) * 4;
        s16x4 lo = *(const s16x4*)vb0;
        s16x4 hi = *(const s16x4*)vb2;
        s16x8 vf;
        vf[0] = lo[0]; vf[1] = lo[1]; vf[2] = lo[2]; vf[3] = lo[3];
        vf[4] = hi[0]; vf[5] = hi[1]; vf[6] = hi[2]; vf[7] = hi[3];
#pragma unroll
        for (int nq = 0; nq < 4; ++nq)
          cacc[md][nq] = __builtin_amdgcn_mfma_f32_16x16x32_bf16(vf, pb[nq], cacc[md][nq], 0, 0, 0);
      }
    }
    __syncthreads();
  }

#pragma unroll
  for (int nq = 0; nq < 4; ++nq) {
    rs[nq] += __shfl_xor(rs[nq], 16, 64);
    rs[nq] += __shfl_xor(rs[nq], 32, 64);
  }
  float* ctxl = (float*)lds;            // [64][129]
  float* rsl  = (float*)(lds + 33024);  // [128]
  if (wk == 1) {
#pragma unroll
    for (int md = 0; md < 4; ++md)
#pragma unroll
      for (int nq = 0; nq < 4; ++nq)
#pragma unroll
        for (int r = 0; r < 4; ++r)
          ctxl[(md * 16 + g * 4 + r) * 129 + wq * 64 + nq * 16 + lk] = cacc[md][nq][r];
    if (lane < 16)
#pragma unroll
      for (int nq = 0; nq < 4; ++nq) rsl[wq * 64 + nq * 16 + lane] = rs[nq];
  }
  __syncthreads();
  if (wk == 0) {
#pragma unroll
    for (int md = 0; md < 4; ++md)
#pragma unroll
      for (int nq = 0; nq < 4; ++nq)
#pragma unroll
        for (int r = 0; r < 4; ++r) {
          const int idx = (md * 16 + g * 4 + r) * 129 + wq * 64 + nq * 16 + lk;
          ctxl[idx] += cacc[md][nq][r];
        }
    if (lane < 16)
#pragma unroll
      for (int nq = 0; nq < 4; ++nq) {
        const int qi = wq * 64 + nq * 16 + lane;
        const float inv = 1.0f / (rsl[qi] + rs[nq]);
        rsl[qi] = inv;
        rinv[(long)bh * 2048 + q0 + qi] = inv;
      }
  }
  __syncthreads();
  const int qr = tid >> 1, half = tid & 1;
  const float inv = rsl[qr];
  u16* dst = ctx + (long)(bh >> 4) * 2097152 + (long)(q0 + qr) * 1024 + (long)(bh & 15) * 64 + half * 32;
#pragma unroll
  for (int c = 0; c < 4; ++c) {
    s16x8 o;
#pragma unroll
    for (int j = 0; j < 8; ++j) {
      const int d = half * 32 + c * 8 + j;
      o[j] = (short)f2bf(ctxl[d * 129 + qr] * inv);
    }
    ((s16x8*)dst)[c] = o;
  }
}

// ---------------- in-place row softmax, rows of 2048 fp32 ----------------
__global__ __launch_bounds__(256) void k_softmax(float* __restrict__ base) {
  float* p = base + (long)blockIdx.x * 2048;
  const int t = threadIdx.x;
  float4 v0 = ((const float4*)p)[t];
  float4 v1 = ((const float4*)p)[t + 256];
  float m = fmaxf(fmaxf(fmaxf(v0.x, v0.y), fmaxf(v0.z, v0.w)),
                  fmaxf(fmaxf(v1.x, v1.y), fmaxf(v1.z, v1.w)));
#pragma unroll
  for (int i = 32; i >= 1; i >>= 1) m = fmaxf(m, __shfl_xor(m, i, 64));
  __shared__ float sm[4], ss[4];
  if ((t & 63) == 0) sm[t >> 6] = m;
  __syncthreads();
  m = fmaxf(fmaxf(sm[0], sm[1]), fmaxf(sm[2], sm[3]));
  float4 e0, e1;
  e0.x = __expf(v0.x - m); e0.y = __expf(v0.y - m); e0.z = __expf(v0.z - m); e0.w = __expf(v0.w - m);
  e1.x = __expf(v1.x - m); e1.y = __expf(v1.y - m); e1.z = __expf(v1.z - m); e1.w = __expf(v1.w - m);
  float s = (e0.x + e0.y + e0.z + e0.w) + (e1.x + e1.y + e1.z + e1.w);
#pragma unroll
  for (int i = 32; i >= 1; i >>= 1) s += __shfl_xor(s, i, 64);
  if ((t & 63) == 0) ss[t >> 6] = s;
  __syncthreads();
  s = ss[0] + ss[1] + ss[2] + ss[3];
  float inv = 1.0f / s;
  e0.x *= inv; e0.y *= inv; e0.z *= inv; e0.w *= inv;
  e1.x *= inv; e1.y *= inv; e1.z *= inv; e1.w *= inv;
  ((float4*)p)[t] = e0;
  ((float4*)p)[t + 256] = e1;
}

// ---------------- launch ----------------
extern "C" void kernel_launch(void* const* d_in, const int* in_sizes, int n_in,
                              void* d_out, int out_size, void* d_ws, size_t ws_size,
                              hipStream_t stream) {
  const float* query = (const float*)d_in[0];
  const float* key   = (const float*)d_in[1];
  const float* value = (const float*)d_in[2];
  const float* Wq = (const float*)d_in[3];
  const float* bq = (const float*)d_in[4];
  const float* Wk = (const float*)d_in[5];
  const float* bk = (const float*)d_in[6];
  const float* Wv = (const float*)d_in[7];
  const float* bv = (const float*)d_in[8];
  const float* Wo = (const float*)d_in[9];
  const float* bo = (const float*)d_in[10];
  const float* Wa = (const float*)d_in[11];
  const float* ba = (const float*)d_in[12];
  float* out = (float*)d_out;
  char* ws = (char*)d_ws;

  // workspace layout (bytes)
  u16* qb  = (u16*)(ws + 0);           // [3][4096,1024] bf16 q,k,v (contiguous)
  u16* Wqt = (u16*)(ws + 25165824);    // [3][1024,1024] Wq^T,Wk^T,Wv^T bf16 (contig; reused as rinv)
  u16* Wot = (u16*)(ws + 31457280);
  u16* Wat = (u16*)(ws + 33554432);    // [3,1024,1024]
  u16* qp  = (u16*)(ws + 39845888);    // [3][4096,1024] projected q,k,v (contiguous)
  u16* kp  = (u16*)(ws + 48234496);
  u16* vp  = (u16*)(ws + 56623104);
  u16* vt  = (u16*)(ws + 65011712);    // [B,H,64,2048] V^T per head
  u16* ctx = (u16*)(ws + 73400320);    // [4096,1024]
  u16* qa  = (u16*)(ws + 81788928);    // [2][3][4096,1024] aspect q then aspect k (contiguous)
  float* rinv  = (float*)(ws + 25165824);   // [32,2048] (overwrites Wqt after proj)
  float* pbias = (float*)(ws + 132120576);  // [3,1024] packed bq,bk,bv

  dim3 b256(256);
  dim3 trb(32, 8);

  // bf16 conversions of q,k,v activations (one launch) + bias pack
  k_cvt3<<<dim3(4096, 3), b256, 0, stream>>>(query, key, value, qb, 1048576);
  k_pack3<<<12, b256, 0, stream>>>(bq, bk, bv, pbias);

  // all weight transposes in ONE launch (z = 0..6)
  k_trW<<<dim3(32, 32, 7), b256, 0, stream>>>(Wq, Wk, Wv, Wo, Wa, Wqt, Wot, Wat);

  // Q/K/V projections in ONE launch (z = 0,1,2) -> qp,kp,vp
  k_gemm_nt<u16, 0><<<dim3(8, 32, 3), b256, 0, stream>>>(
      qb, Wqt, qp, pbias, nullptr, 1.0f, 1024, 1024, 1024, 1024,
      0, 4194304, 0, 1048576, 0, 4194304, 1024, 3);

  // aspect projections of q and k in ONE launch (z1 = q/k, z2 = aspect)
  k_gemm_nt<u16, 0><<<dim3(8, 32, 6), b256, 0, stream>>>(
      qb, Wat, qa, ba, nullptr, 1.0f, 1024, 1024, 1024, 1024,
      4194304, 0, 0, 1048576, 12582912, 4194304, 1024, 3);

  // per-head V^T: vt[b,h][d][s]  (z = b*16+h)
  k_tr<false><<<dim3(2, 64, 32), trb, 0, stream>>>(
      vp, vt, 1024, 2048, 2097152, 64, 131072, 16);

  // flash attention: ctx (bf16) + rinv
  k_flash<<<dim3(16, 32), b256, 0, stream>>>(qp, kp, vt, ctx, rinv);

  // attn_weights = exp(QK^T * scale) * rinv  -> d_out (single write pass, K=64)
  k_gemm_nt<float, 1><<<dim3(16, 16, 32), b256, 0, stream>>>(
      qp, kp, out + AW_OFF, nullptr, rinv, 0.125f, 64, 1024, 1024, 2048,
      2097152, 64, 2097152, 64, 67108864, 4194304, 0, 16);

  // full-dim pattern logits -> d_out patterns region (z = a*2+b)
  k_gemm_nt<float, 0><<<dim3(16, 16, 6), b256, 0, stream>>>(
      qa, qa + 12582912, out + PAT_OFF, nullptr, nullptr, 0.125f, 1024, 1024, 1024, 2048,
      0, 2097152, 0, 2097152, 0, 4194304, 0, 6);

  // softmax over patterns only (3*B*S = 12288 rows of 2048)
  k_softmax<<<12288, b256, 0, stream>>>(out + PAT_OFF);

  // output projection -> d_out attn_output
  k_gemm_nt<float, 0><<<dim3(8, 32, 1), b256, 0, stream>>>(
      ctx, Wot, out, bo, nullptr, 1.0f, 1024, 1024, 1024, 1024, 0, 0, 0, 0, 0, 0, 0, 1);
}

// Round 9
// 508.217 us; speedup vs baseline: 1.1203x; 1.0483x over previous
//
#include <hip/hip_runtime.h>

typedef unsigned short u16;
typedef short s16x4 __attribute__((ext_vector_type(4)));
typedef short s16x8 __attribute__((ext_vector_type(8)));
typedef float f32x4 __attribute__((ext_vector_type(4)));

#define DEVFN __device__ __forceinline__

// problem constants
constexpr long AW_OFF  = 4194304;               // attn_output elems (2*2048*1024)
constexpr long PAT_OFF = AW_OFF + 134217728;    // + attn_weights elems (2*16*2048*2048)
constexpr float EXPSC  = 0.18033688011f;        // 0.125 * log2(e)

DEVFN u16 f2bf(float x) {
  unsigned u = __builtin_bit_cast(unsigned, x);
  unsigned r = (u + 0x7fffu + ((u >> 16) & 1u)) >> 16;   // RNE
  return (u16)r;
}

DEVFN void gld16(const u16* g, u16* l) {
  __builtin_amdgcn_global_load_lds(
      (const __attribute__((address_space(1))) unsigned int*)g,
      (__attribute__((address_space(3))) unsigned int*)l, 16, 0, 0);
}

// ---------------- fp32 -> bf16 elementwise, 3 tensors ----------------
__global__ __launch_bounds__(256) void k_cvt3(const float* __restrict__ a,
                                              const float* __restrict__ b,
                                              const float* __restrict__ c,
                                              u16* __restrict__ out, int n4) {
  int i = blockIdx.x * 256 + threadIdx.x;
  if (i >= n4) return;
  const float* in = (blockIdx.y == 0) ? a : (blockIdx.y == 1) ? b : c;
  float4 v = ((const float4*)in)[i];
  s16x4 o; o[0] = f2bf(v.x); o[1] = f2bf(v.y); o[2] = f2bf(v.z); o[3] = f2bf(v.w);
  ((s16x4*)(out + (long)blockIdx.y * 4194304))[i] = o;
}

// ---------------- pack 3 bias vectors contiguous ----------------
__global__ __launch_bounds__(256) void k_pack3(const float* __restrict__ a,
                                               const float* __restrict__ b,
                                               const float* __restrict__ c,
                                               float* __restrict__ out) {
  int i = blockIdx.x * 256 + threadIdx.x;   // grid 12 -> 3072
  const float* in = (i < 1024) ? a : (i < 2048) ? b : c;
  out[i] = in[i & 1023];
}

// ---------------- merged weight transposes: 7 slices of [1024,1024] ----------------
__global__ __launch_bounds__(256) void k_trW(const float* __restrict__ Wq,
                                             const float* __restrict__ Wk,
                                             const float* __restrict__ Wv,
                                             const float* __restrict__ Wo,
                                             const float* __restrict__ Wa,
                                             u16* __restrict__ Wqt,
                                             u16* __restrict__ Wot,
                                             u16* __restrict__ Wat) {
  __shared__ u16 tile[32][33];
  const int z = blockIdx.z;
  const float* in;
  u16* outp;
  if (z == 0)      { in = Wq; outp = Wqt; }
  else if (z == 1) { in = Wk; outp = Wqt + 1048576; }
  else if (z == 2) { in = Wv; outp = Wqt + 2097152; }
  else if (z == 3) { in = Wo; outp = Wot; }
  else             { in = Wa + (long)(z - 4) * 1048576; outp = Wat + (long)(z - 4) * 1048576; }
  int k0 = blockIdx.y * 32, n0 = blockIdx.x * 32;
  int tx = threadIdx.x & 31, ty = threadIdx.x >> 5;
#pragma unroll
  for (int i = 0; i < 4; ++i)
    tile[ty + i * 8][tx] = f2bf(in[(long)(k0 + ty + i * 8) * 1024 + (n0 + tx)]);
  __syncthreads();
#pragma unroll
  for (int i = 0; i < 4; ++i)
    outp[(long)(n0 + ty + i * 8) * 1024 + (k0 + tx)] = tile[tx][ty + i * 8];
}

// ---------------- tiled transpose: out[n][k] = bf16(in[k][n]) ----------------
template <bool IN_F32>
__global__ __launch_bounds__(256) void k_tr(const void* __restrict__ inv,
                                            u16* __restrict__ out,
                                            long ldin, long ldout,
                                            long inz1, long inz2, long outz, int zdiv) {
  __shared__ u16 tile[32][33];
  int z = blockIdx.z;
  long ioff = (long)(z / zdiv) * inz1 + (long)(z % zdiv) * inz2;
  int k0 = blockIdx.y * 32, n0 = blockIdx.x * 32;
  int tx = threadIdx.x, ty = threadIdx.y;
#pragma unroll
  for (int i = 0; i < 4; ++i) {
    long k = k0 + ty + i * 8, n = n0 + tx;
    u16 v;
    if constexpr (IN_F32) v = f2bf(((const float*)inv)[ioff + k * ldin + n]);
    else                  v = ((const u16*)inv)[ioff + k * ldin + n];
    tile[ty + i * 8][tx] = v;
  }
  __syncthreads();
  long ooff = (long)z * outz;
#pragma unroll
  for (int i = 0; i < 4; ++i) {
    long n = n0 + ty + i * 8, k = k0 + tx;
    out[ooff + n * ldout + k] = tile[tx][ty + i * 8];
  }
}

// ---------------- batched NT GEMM: C = f(alpha * A[M,K] @ B[N,K]^T) ----------------
// EPI 0: v = alpha*acc + bias[z2][col];  EPI 1: v = exp2(acc*EXPSC) * rinv[z][row]
template <typename OutT, int EPI>
__global__ __launch_bounds__(256) void k_gemm_nt(
    const u16* __restrict__ Ap, const u16* __restrict__ Bp, OutT* __restrict__ Cp,
    const float* __restrict__ bias, const float* __restrict__ rinv, float alpha, int K,
    long lda, long ldb, long ldc,
    long saz1, long saz2, long sbz1, long sbz2, long scz1, long scz2,
    long sbias, int zdiv) {
  __shared__ __align__(16) u16 At[128][64];
  __shared__ __align__(16) u16 Bt[128][64];
  const int tid = threadIdx.x, lane = tid & 63, wid = tid >> 6;
  const int wm = wid >> 1, wn = wid & 1;

  const int gx = gridDim.x, gy = gridDim.y;
  int id = (blockIdx.z * gy + blockIdx.y) * gx + blockIdx.x;
  const int nb = gx * gy * (int)gridDim.z;
  if ((nb & 7) == 0) id = (id & 7) * (nb >> 3) + (id >> 3);
  const int bxi = id % gx, byi = (id / gx) % gy, bzi = id / (gx * gy);

  const int z = bzi, z1 = z / zdiv, z2 = z % zdiv;
  const u16* Ab = Ap + (long)z1 * saz1 + (long)z2 * saz2;
  const u16* Bb = Bp + (long)z1 * sbz1 + (long)z2 * sbz2;
  OutT* C = Cp + (long)z1 * scz1 + (long)z2 * scz2;
  const float* bv = bias ? bias + (long)z2 * sbias : nullptr;
  const int row0 = byi * 128, col0 = bxi * 128;
  const int lk = lane & 15, g = lane >> 4;

  f32x4 acc[4][4] = {};

  for (int k0 = 0; k0 < K; k0 += 64) {
#pragma unroll
    for (int it = 0; it < 4; ++it) {
      const int u = it * 256 + tid;          // 16B-unit index over the tile
      const int r = u >> 3, p = u & 7;       // row, physical unit in row
      const int cg = (p ^ (r & 7)) * 8;      // pre-swizzled source column (elems)
      gld16(Ab + (long)(row0 + r) * lda + (k0 + cg), &At[r][p * 8]);
      gld16(Bb + (long)(col0 + r) * ldb + (k0 + cg), &Bt[r][p * 8]);
    }
    __syncthreads();
#pragma unroll
    for (int kk = 0; kk < 2; ++kk) {
      s16x8 af[4], bf[4];
#pragma unroll
      for (int m = 0; m < 4; ++m)
        af[m] = *(const s16x8*)&At[wm * 64 + m * 16 + lk][((kk * 4 + g) ^ (lk & 7)) * 8];
#pragma unroll
      for (int n = 0; n < 4; ++n)
        bf[n] = *(const s16x8*)&Bt[wn * 64 + n * 16 + lk][((kk * 4 + g) ^ (lk & 7)) * 8];
#pragma unroll
      for (int m = 0; m < 4; ++m)
#pragma unroll
        for (int n = 0; n < 4; ++n)
          acc[m][n] = __builtin_amdgcn_mfma_f32_16x16x32_bf16(af[m], bf[n], acc[m][n], 0, 0, 0);
    }
    __syncthreads();
  }

  const float* rz = (EPI == 1) ? rinv + (long)z * 2048 : nullptr;
#pragma unroll
  for (int m = 0; m < 4; ++m) {
    const int grow = row0 + wm * 64 + m * 16 + g * 4;
#pragma unroll
    for (int r = 0; r < 4; ++r) {
      float iv = 0.0f;
      if constexpr (EPI == 1) iv = rz[grow + r];
#pragma unroll
      for (int n = 0; n < 4; ++n) {
        const int gcol = col0 + wn * 64 + n * 16 + lk;
        float v;
        if constexpr (EPI == 1) v = exp2f(acc[m][n][r] * EXPSC) * iv;
        else                    v = alpha * acc[m][n][r] + (bv ? bv[gcol] : 0.0f);
        if constexpr (sizeof(OutT) == 2) C[(long)(grow + r) * ldc + gcol] = f2bf(v);
        else                             C[(long)(grow + r) * ldc + gcol] = v;
      }
    }
  }
}

// ---------------- 256x128 3-buffer pipelined NT GEMM (K = NT*64, NT >= 3) ----------------
// 8 waves as 4M x 2N; per-wave inner loop identical to k_gemm_nt (acc[4][4], swizzled
// ds_read_b128). 3 LDS K-tile buffers (144 KiB dynamic): stage(t+3) issued after the
// barrier ending all reads of buf t%3 -> 2 iterations of HBM latency cover. Counted
// vmcnt (never 0 mid-loop) + raw s_barrier + sched_barrier fences (T3/T4).
template <typename OutT, bool BIAS>
__global__ __launch_bounds__(512, 1) void k_gemm3p(
    const u16* __restrict__ Ap, const u16* __restrict__ Bp, OutT* __restrict__ Cp,
    const float* __restrict__ bias, float alpha, int K,
    long lda, long ldb, long ldc,
    long saz1, long saz2, long sbz1, long sbz2, long scz1, long scz2,
    long sbias, int zdiv) {
  extern __shared__ __align__(16) u16 dyn[];   // buf i: A[256][64] @ i*24576, B[128][64] @ +16384
  const int tid = threadIdx.x, lane = tid & 63, wid = tid >> 6;
  const int wm = wid >> 1, wn = wid & 1;       // 4M x 2N

  const int gx = gridDim.x, gy = gridDim.y;
  int id = (blockIdx.z * gy + blockIdx.y) * gx + blockIdx.x;
  const int nb = gx * gy * (int)gridDim.z;
  if ((nb & 7) == 0) id = (id & 7) * (nb >> 3) + (id >> 3);
  const int bxi = id % gx, byi = (id / gx) % gy, bzi = id / (gx * gy);

  const int z = bzi, z1 = z / zdiv, z2 = z % zdiv;
  const u16* Ab = Ap + (long)z1 * saz1 + (long)z2 * saz2;
  const u16* Bb = Bp + (long)z1 * sbz1 + (long)z2 * sbz2;
  OutT* C = Cp + (long)z1 * scz1 + (long)z2 * scz2;
  const float* bv = BIAS ? bias + (long)z2 * sbias : nullptr;
  const int row0 = byi * 256, col0 = bxi * 128;
  const int lk = lane & 15, g = lane >> 4;

  f32x4 acc[4][4] = {};
  const int NT = K >> 6;

  auto STAGE = [&](int t, int bi) {
    const int k0 = t << 6;
    u16* Ax = dyn + bi * 24576;
    u16* Bx = dyn + bi * 24576 + 16384;
#pragma unroll
    for (int it = 0; it < 4; ++it) {           // A: 256x64 = 2048 units
      const int u = it * 512 + tid;
      const int r = u >> 3, p = u & 7;
      const int cg = (p ^ (r & 7)) * 8;
      gld16(Ab + (long)(row0 + r) * lda + (k0 + cg), Ax + r * 64 + p * 8);
    }
#pragma unroll
    for (int it = 0; it < 2; ++it) {           // B: 128x64 = 1024 units
      const int u = it * 512 + tid;
      const int r = u >> 3, p = u & 7;
      const int cg = (p ^ (r & 7)) * 8;
      gld16(Bb + (long)(col0 + r) * ldb + (k0 + cg), Bx + r * 64 + p * 8);
    }
  };

  STAGE(0, 0); STAGE(1, 1); STAGE(2, 2);
  int bi = 0;
  for (int t = 0; t < NT; ++t) {
    // wait tile t landed; keep tiles t+1,t+2 (6 loads each, per wave) in flight
    if (t + 2 < NT)      asm volatile("s_waitcnt vmcnt(12)" ::: "memory");
    else if (t + 1 < NT) asm volatile("s_waitcnt vmcnt(6)" ::: "memory");
    else                 asm volatile("s_waitcnt vmcnt(0)" ::: "memory");
    __builtin_amdgcn_sched_barrier(0);
    __builtin_amdgcn_s_barrier();
    __builtin_amdgcn_sched_barrier(0);
    const u16* Ax = dyn + bi * 24576;
    const u16* Bx = dyn + bi * 24576 + 16384;
#pragma unroll
    for (int kk = 0; kk < 2; ++kk) {
      s16x8 af[4], bf[4];
#pragma unroll
      for (int m = 0; m < 4; ++m)
        af[m] = *(const s16x8*)(Ax + (wm * 64 + m * 16 + lk) * 64 + ((kk * 4 + g) ^ (lk & 7)) * 8);
#pragma unroll
      for (int n = 0; n < 4; ++n)
        bf[n] = *(const s16x8*)(Bx + (wn * 64 + n * 16 + lk) * 64 + ((kk * 4 + g) ^ (lk & 7)) * 8);
      __builtin_amdgcn_s_setprio(1);
#pragma unroll
      for (int m = 0; m < 4; ++m)
#pragma unroll
        for (int n = 0; n < 4; ++n)
          acc[m][n] = __builtin_amdgcn_mfma_f32_16x16x32_bf16(af[m], bf[n], acc[m][n], 0, 0, 0);
      __builtin_amdgcn_s_setprio(0);
    }
    __builtin_amdgcn_sched_barrier(0);
    __builtin_amdgcn_s_barrier();
    __builtin_amdgcn_sched_barrier(0);
    if (t + 3 < NT) STAGE(t + 3, bi);
    bi = (bi == 2) ? 0 : bi + 1;
  }

#pragma unroll
  for (int m = 0; m < 4; ++m) {
    const int grow = row0 + wm * 64 + m * 16 + g * 4;
#pragma unroll
    for (int r = 0; r < 4; ++r) {
#pragma unroll
      for (int n = 0; n < 4; ++n) {
        const int gcol = col0 + wn * 64 + n * 16 + lk;
        float v = alpha * acc[m][n][r] + (BIAS ? bv[gcol] : 0.0f);
        if constexpr (sizeof(OutT) == 2) C[(long)(grow + r) * ldc + gcol] = f2bf(v);
        else                             C[(long)(grow + r) * ldc + gcol] = v;
      }
    }
  }
}

// ---------------- flash attention: ctx[b,s,h*64+d], rinv[bh,q] = 1/sum(exp) ----------------
__global__ __launch_bounds__(256) void k_flash(
    const u16* __restrict__ qp, const u16* __restrict__ kp, const u16* __restrict__ vt,
    u16* __restrict__ ctx, float* __restrict__ rinv) {
  __shared__ __align__(16) char lds[49152];
  u16* Qt = (u16*)lds;            // [128][64]
  u16* Kt = (u16*)(lds + 16384);  // [128][64]
  u16* Vl = (u16*)(lds + 32768);  // [64][128]
  const int tid = threadIdx.x, lane = tid & 63, wid = tid >> 6;
  const int wk = wid >> 1, wq = wid & 1;

  const int gx = gridDim.x;
  int id = blockIdx.y * gx + blockIdx.x;
  const int nb = gx * (int)gridDim.y;
  if ((nb & 7) == 0) id = (id & 7) * (nb >> 3) + (id >> 3);
  const int bh = id / gx, q0 = (id % gx) * 128;

  const long qkbase = (long)(bh >> 4) * 2097152 + (long)(bh & 15) * 64;
  const long vbase = (long)bh * 131072;
  const int lk = lane & 15, g = lane >> 4;
  const int sp = lane & 7;
  const int sr = lane >> 3;

#pragma unroll
  for (int i = 0; i < 4; ++i) {
    const int rr = (wid * 4 + i) * 8 + sr;
    gld16(qp + qkbase + (long)(q0 + rr) * 1024 + ((sp ^ (rr & 7)) * 8), Qt + rr * 64 + sp * 8);
  }
  __syncthreads();

  s16x8 qf[2][4];
#pragma unroll
  for (int kk = 0; kk < 2; ++kk) {
#pragma unroll
    for (int nq = 0; nq < 4; ++nq)
      qf[kk][nq] = *(const s16x8*)(Qt + (wq * 64 + nq * 16 + lk) * 64 + ((kk * 4 + g) ^ (lk & 7)) * 8);
  }

  f32x4 cacc[4][4] = {};
  float rs[4] = {0.f, 0.f, 0.f, 0.f};

  for (int t = 0; t < 16; ++t) {
    const int kb = t * 128;
#pragma unroll
    for (int i = 0; i < 4; ++i) {
      const int rr = (wid * 4 + i) * 8 + sr;
      gld16(kp + qkbase + (long)(kb + rr) * 1024 + ((sp ^ (rr & 7)) * 8), Kt + rr * 64 + sp * 8);
      const int dd = (wid * 4 + i) * 4 + g;
      const int pv = lane & 15;
      const int cv = (pv & 8) | ((pv ^ dd) & 7);
      gld16(vt + vbase + (long)dd * 2048 + (kb + cv * 8), Vl + dd * 128 + pv * 8);
    }
    __syncthreads();

    f32x4 st[4][4] = {};
#pragma unroll
    for (int kk = 0; kk < 2; ++kk) {
      s16x8 af[4];
#pragma unroll
      for (int mk = 0; mk < 4; ++mk)
        af[mk] = *(const s16x8*)(Kt + (wk * 64 + mk * 16 + lk) * 64 + ((kk * 4 + g) ^ (lk & 7)) * 8);
#pragma unroll
      for (int mk = 0; mk < 4; ++mk)
#pragma unroll
        for (int nq = 0; nq < 4; ++nq)
          st[mk][nq] = __builtin_amdgcn_mfma_f32_16x16x32_bf16(af[mk], qf[kk][nq], st[mk][nq], 0, 0, 0);
    }
#pragma unroll
    for (int mk = 0; mk < 4; ++mk)
#pragma unroll
      for (int nq = 0; nq < 4; ++nq)
#pragma unroll
        for (int j = 0; j < 4; ++j) {
          const float p = exp2f(st[mk][nq][j] * EXPSC);
          st[mk][nq][j] = p;
          rs[nq] += p;
        }
#pragma unroll
    for (int ks = 0; ks < 2; ++ks) {
      s16x8 pb[4];
#pragma unroll
      for (int nq = 0; nq < 4; ++nq) {
        s16x8 b;
#pragma unroll
        for (int j = 0; j < 4; ++j) {
          b[j]     = (short)f2bf(st[2 * ks][nq][j]);
          b[4 + j] = (short)f2bf(st[2 * ks + 1][nq][j]);
        }
        pb[nq] = b;
      }
#pragma unroll
      for (int md = 0; md < 4; ++md) {
        const int rowv = md * 16 + lk;
        const int u0 = ks * 4 + (g >> 1);
        const int p0 = wk * 8 + ((u0 ^ (rowv & 7)) & 7);
        const int p2 = wk * 8 + (((u0 + 2) ^ (rowv & 7)) & 7);
        const u16* vb0 = Vl + rowv * 128 + p0 * 8 + (g & 1) * 4;
        const u16* vb2 = Vl + rowv * 128 + p2 * 8 + (g & 1) * 4;
        s16x4 lo = *(const s16x4*)vb0;
        s16x4 hi = *(const s16x4*)vb2;
        s16x8 vf;
        vf[0] = lo[0]; vf[1] = lo[1]; vf[2] = lo[2]; vf[3] = lo[3];
        vf[4] = hi[0]; vf[5] = hi[1]; vf[6] = hi[2]; vf[7] = hi[3];
#pragma unroll
        for (int nq = 0; nq < 4; ++nq)
          cacc[md][nq] = __builtin_amdgcn_mfma_f32_16x16x32_bf16(vf, pb[nq], cacc[md][nq], 0, 0, 0);
      }
    }
    __syncthreads();
  }

#pragma unroll
  for (int nq = 0; nq < 4; ++nq) {
    rs[nq] += __shfl_xor(rs[nq], 16, 64);
    rs[nq] += __shfl_xor(rs[nq], 32, 64);
  }
  float* ctxl = (float*)lds;            // [64][129]
  float* rsl  = (float*)(lds + 33024);  // [128]
  if (wk == 1) {
#pragma unroll
    for (int md = 0; md < 4; ++md)
#pragma unroll
      for (int nq = 0; nq < 4; ++nq)
#pragma unroll
        for (int r = 0; r < 4; ++r)
          ctxl[(md * 16 + g * 4 + r) * 129 + wq * 64 + nq * 16 + lk] = cacc[md][nq][r];
    if (lane < 16)
#pragma unroll
      for (int nq = 0; nq < 4; ++nq) rsl[wq * 64 + nq * 16 + lane] = rs[nq];
  }
  __syncthreads();
  if (wk == 0) {
#pragma unroll
    for (int md = 0; md < 4; ++md)
#pragma unroll
      for (int nq = 0; nq < 4; ++nq)
#pragma unroll
        for (int r = 0; r < 4; ++r) {
          const int idx = (md * 16 + g * 4 + r) * 129 + wq * 64 + nq * 16 + lk;
          ctxl[idx] += cacc[md][nq][r];
        }
    if (lane < 16)
#pragma unroll
      for (int nq = 0; nq < 4; ++nq) {
        const int qi = wq * 64 + nq * 16 + lane;
        const float inv = 1.0f / (rsl[qi] + rs[nq]);
        rsl[qi] = inv;
        rinv[(long)bh * 2048 + q0 + qi] = inv;
      }
  }
  __syncthreads();
  const int qr = tid >> 1, half = tid & 1;
  const float inv = rsl[qr];
  u16* dst = ctx + (long)(bh >> 4) * 2097152 + (long)(q0 + qr) * 1024 + (long)(bh & 15) * 64 + half * 32;
#pragma unroll
  for (int c = 0; c < 4; ++c) {
    s16x8 o;
#pragma unroll
    for (int j = 0; j < 8; ++j) {
      const int d = half * 32 + c * 8 + j;
      o[j] = (short)f2bf(ctxl[d * 129 + qr] * inv);
    }
    ((s16x8*)dst)[c] = o;
  }
}

// ---------------- in-place row softmax, rows of 2048 fp32 ----------------
__global__ __launch_bounds__(256) void k_softmax(float* __restrict__ base) {
  float* p = base + (long)blockIdx.x * 2048;
  const int t = threadIdx.x;
  float4 v0 = ((const float4*)p)[t];
  float4 v1 = ((const float4*)p)[t + 256];
  float m = fmaxf(fmaxf(fmaxf(v0.x, v0.y), fmaxf(v0.z, v0.w)),
                  fmaxf(fmaxf(v1.x, v1.y), fmaxf(v1.z, v1.w)));
#pragma unroll
  for (int i = 32; i >= 1; i >>= 1) m = fmaxf(m, __shfl_xor(m, i, 64));
  __shared__ float sm[4], ss[4];
  if ((t & 63) == 0) sm[t >> 6] = m;
  __syncthreads();
  m = fmaxf(fmaxf(sm[0], sm[1]), fmaxf(sm[2], sm[3]));
  float4 e0, e1;
  e0.x = __expf(v0.x - m); e0.y = __expf(v0.y - m); e0.z = __expf(v0.z - m); e0.w = __expf(v0.w - m);
  e1.x = __expf(v1.x - m); e1.y = __expf(v1.y - m); e1.z = __expf(v1.z - m); e1.w = __expf(v1.w - m);
  float s = (e0.x + e0.y + e0.z + e0.w) + (e1.x + e1.y + e1.z + e1.w);
#pragma unroll
  for (int i = 32; i >= 1; i >>= 1) s += __shfl_xor(s, i, 64);
  if ((t & 63) == 0) ss[t >> 6] = s;
  __syncthreads();
  s = ss[0] + ss[1] + ss[2] + ss[3];
  float inv = 1.0f / s;
  e0.x *= inv; e0.y *= inv; e0.z *= inv; e0.w *= inv;
  e1.x *= inv; e1.y *= inv; e1.z *= inv; e1.w *= inv;
  ((float4*)p)[t] = e0;
  ((float4*)p)[t + 256] = e1;
}

// ---------------- launch ----------------
extern "C" void kernel_launch(void* const* d_in, const int* in_sizes, int n_in,
                              void* d_out, int out_size, void* d_ws, size_t ws_size,
                              hipStream_t stream) {
  const float* query = (const float*)d_in[0];
  const float* key   = (const float*)d_in[1];
  const float* value = (const float*)d_in[2];
  const float* Wq = (const float*)d_in[3];
  const float* bq = (const float*)d_in[4];
  const float* Wk = (const float*)d_in[5];
  const float* bk = (const float*)d_in[6];
  const float* Wv = (const float*)d_in[7];
  const float* bv = (const float*)d_in[8];
  const float* Wo = (const float*)d_in[9];
  const float* bo = (const float*)d_in[10];
  const float* Wa = (const float*)d_in[11];
  const float* ba = (const float*)d_in[12];
  float* out = (float*)d_out;
  char* ws = (char*)d_ws;

  // workspace layout (bytes)
  u16* qb  = (u16*)(ws + 0);           // [3][4096,1024] bf16 q,k,v (contiguous)
  u16* Wqt = (u16*)(ws + 25165824);    // [3][1024,1024] Wq^T,Wk^T,Wv^T bf16 (contig; reused as rinv)
  u16* Wot = (u16*)(ws + 31457280);
  u16* Wat = (u16*)(ws + 33554432);    // [3,1024,1024]
  u16* qp  = (u16*)(ws + 39845888);    // [3][4096,1024] projected q,k,v (contiguous)
  u16* kp  = (u16*)(ws + 48234496);
  u16* vp  = (u16*)(ws + 56623104);
  u16* vt  = (u16*)(ws + 65011712);    // [B,H,64,2048] V^T per head
  u16* ctx = (u16*)(ws + 73400320);    // [4096,1024]
  u16* qa  = (u16*)(ws + 81788928);    // [2][3][4096,1024] aspect q then aspect k (contiguous)
  float* rinv  = (float*)(ws + 25165824);   // [32,2048] (overwrites Wqt after proj)
  float* pbias = (float*)(ws + 132120576);  // [3,1024] packed bq,bk,bv

  // allow 144 KiB dynamic LDS for the pipelined GEMM (idempotent)
  hipFuncSetAttribute((const void*)k_gemm3p<u16, true>,
                      hipFuncAttributeMaxDynamicSharedMemorySize, 147456);
  hipFuncSetAttribute((const void*)k_gemm3p<float, false>,
                      hipFuncAttributeMaxDynamicSharedMemorySize, 147456);

  dim3 b256(256), b512(512);
  dim3 trb(32, 8);

  // bf16 conversions of q,k,v activations (one launch) + bias pack
  k_cvt3<<<dim3(4096, 3), b256, 0, stream>>>(query, key, value, qb, 1048576);
  k_pack3<<<12, b256, 0, stream>>>(bq, bk, bv, pbias);

  // all weight transposes in ONE launch (z = 0..6)
  k_trW<<<dim3(32, 32, 7), b256, 0, stream>>>(Wq, Wk, Wv, Wo, Wa, Wqt, Wot, Wat);

  // Q/K/V projections in ONE launch (z = 0,1,2) -> qp,kp,vp
  k_gemm_nt<u16, 0><<<dim3(8, 32, 3), b256, 0, stream>>>(
      qb, Wqt, qp, pbias, nullptr, 1.0f, 1024, 1024, 1024, 1024,
      0, 4194304, 0, 1048576, 0, 4194304, 1024, 3);

  // aspect projections of q and k in ONE pipelined launch (768 blocks, 256x128)
  k_gemm3p<u16, true><<<dim3(8, 16, 6), b512, 147456, stream>>>(
      qb, Wat, qa, ba, 1.0f, 1024, 1024, 1024, 1024,
      4194304, 0, 0, 1048576, 12582912, 4194304, 1024, 3);

  // per-head V^T: vt[b,h][d][s]  (z = b*16+h)
  k_tr<false><<<dim3(2, 64, 32), trb, 0, stream>>>(
      vp, vt, 1024, 2048, 2097152, 64, 131072, 16);

  // flash attention: ctx (bf16) + rinv
  k_flash<<<dim3(16, 32), b256, 0, stream>>>(qp, kp, vt, ctx, rinv);

  // attn_weights = exp(QK^T * scale) * rinv  -> d_out (single write pass, K=64)
  k_gemm_nt<float, 1><<<dim3(16, 16, 32), b256, 0, stream>>>(
      qp, kp, out + AW_OFF, nullptr, rinv, 0.125f, 64, 1024, 1024, 2048,
      2097152, 64, 2097152, 64, 67108864, 4194304, 0, 16);

  // full-dim pattern logits -> d_out patterns region (768 blocks, 256x128)
  k_gemm3p<float, false><<<dim3(16, 8, 6), b512, 147456, stream>>>(
      qa, qa + 12582912, out + PAT_OFF, nullptr, 0.125f, 1024, 1024, 1024, 2048,
      0, 2097152, 0, 2097152, 0, 4194304, 0, 6);

  // softmax over patterns only (3*B*S = 12288 rows of 2048)
  k_softmax<<<12288, b256, 0, stream>>>(out + PAT_OFF);

  // output projection -> d_out attn_output
  k_gemm_nt<float, 0><<<dim3(8, 32, 1), b256, 0, stream>>>(
      ctx, Wot, out, bo, nullptr, 1.0f, 1024, 1024, 1024, 1024, 0, 0, 0, 0, 0, 0, 0, 1);
}